// Round 1
// baseline (190.683 us; speedup 1.0000x reference)
//
#include <hip/hip_runtime.h>
#include <math.h>

// MoE router: logits = x @ gate_w  (M=32768, K=2048, N=64 fp32)
// outputs (concat flat, all read back as float32):
//   [0 .. 2N)      top_k_weights  [N,2]
//   [2N .. 4N)     top_k_indices  [N,2]  (stored as float values)
//   [4N]           load_balance_loss scalar
#define N_TOKENS 32768
#define HIDDEN   2048
#define NEXP     64
#define BM 64          // tokens per block
#define BK 64          // K chunk
#define BMP 68         // padded token dim for transposed x tile (16B-aligned rows, bank spread)
#define NBLK (N_TOKENS / BM)   // 512 blocks

__global__ __launch_bounds__(256, 2)
void router_main(const float* __restrict__ x, const float* __restrict__ gw,
                 float* __restrict__ out_w, float* __restrict__ out_i,
                 float* __restrict__ wsP, int* __restrict__ wsC)
{
    // K-loop staging area; after the K-loop the same memory is reused for logits.
    __shared__ __align__(16) char smem_raw[BK * BMP * 4 + BK * NEXP * 4]; // 17408 + 16384 B
    float (*xt)[BMP]      = reinterpret_cast<float(*)[BMP]>(smem_raw);          // [BK][BMP] transposed x
    float (*wt)[NEXP]     = reinterpret_cast<float(*)[NEXP]>(smem_raw + BK * BMP * 4); // [BK][64]
    float (*logits)[NEXP] = reinterpret_cast<float(*)[NEXP]>(smem_raw);         // [BM][64] (aliases xt)
    __shared__ float pred[4][NEXP];
    __shared__ int   cntl[NEXP];

    const int tid = threadIdx.x;
    const int m0  = blockIdx.x * BM;
    if (tid < NEXP) cntl[tid] = 0;

    const int te = tid & 15;   // expert group: experts te*4 .. te*4+3
    const int tm = tid >> 4;   // token group:  tokens  tm*4 .. tm*4+3

    float acc[4][4];
    #pragma unroll
    for (int i = 0; i < 4; ++i)
        #pragma unroll
        for (int j = 0; j < 4; ++j) acc[i][j] = 0.f;

    for (int k0 = 0; k0 < HIDDEN; k0 += BK) {
        __syncthreads();
        // stage gate_w tile [BK][64]: 1024 float4, coalesced, layout matches global
        const float4* wg4 = reinterpret_cast<const float4*>(gw + (size_t)k0 * NEXP);
        float4* wt4 = reinterpret_cast<float4*>(&wt[0][0]);
        #pragma unroll
        for (int r = 0; r < 4; ++r) wt4[tid + 256 * r] = wg4[tid + 256 * r];
        // stage x tile transposed -> xt[k][m]; global reads coalesced float4
        #pragma unroll
        for (int r = 0; r < 4; ++r) {
            int idx = tid + 256 * r;          // 0..1023
            int m   = idx >> 4;               // 64 tokens, 16 float4 per token row
            int f4  = idx & 15;
            const float4 v =
                reinterpret_cast<const float4*>(x + (size_t)(m0 + m) * HIDDEN + k0)[f4];
            int kk = f4 * 4;
            xt[kk + 0][m] = v.x;
            xt[kk + 1][m] = v.y;
            xt[kk + 2][m] = v.z;
            xt[kk + 3][m] = v.w;
        }
        __syncthreads();
        #pragma unroll
        for (int k = 0; k < BK; ++k) {
            const float4 wv = *reinterpret_cast<const float4*>(&wt[k][te * 4]);
            const float4 xv = *reinterpret_cast<const float4*>(&xt[k][tm * 4]);
            const float xr[4] = {xv.x, xv.y, xv.z, xv.w};
            const float wr[4] = {wv.x, wv.y, wv.z, wv.w};
            #pragma unroll
            for (int i = 0; i < 4; ++i)
                #pragma unroll
                for (int j = 0; j < 4; ++j)
                    acc[i][j] = fmaf(xr[i], wr[j], acc[i][j]);
        }
    }
    __syncthreads();
    // dump logits into LDS (reuses the staging area)
    #pragma unroll
    for (int i = 0; i < 4; ++i) {
        float4 v = make_float4(acc[i][0], acc[i][1], acc[i][2], acc[i][3]);
        *reinterpret_cast<float4*>(&logits[tm * 4 + i][te * 4]) = v;
    }
    __syncthreads();

    // epilogue: one wave handles BM/4 tokens, lane = expert
    const int wave = tid >> 6;
    const int lane = tid & 63;
    const int TPW  = BM / 4;   // 16 tokens per wave
    float sumP = 0.f;          // per-lane: sum of probs for expert==lane
    for (int t = 0; t < TPW; ++t) {
        const int m = wave * TPW + t;
        const float l = logits[m][lane];
        // top-1 (max value, lowest index on tie — matches jax.lax.top_k)
        float v = l; int idx = lane;
        #pragma unroll
        for (int off = 32; off >= 1; off >>= 1) {
            float ov = __shfl_xor(v, off);
            int   oi = __shfl_xor(idx, off);
            if (ov > v || (ov == v && oi < idx)) { v = ov; idx = oi; }
        }
        const float v1 = v; const int i1 = idx;
        // top-2
        v = (lane == i1) ? -INFINITY : l;
        idx = lane;
        #pragma unroll
        for (int off = 32; off >= 1; off >>= 1) {
            float ov = __shfl_xor(v, off);
            int   oi = __shfl_xor(idx, off);
            if (ov > v || (ov == v && oi < idx)) { v = ov; idx = oi; }
        }
        const float v2 = v; const int i2 = idx;
        // softmax over the two top logits (stable: v2 - v1 <= 0)
        const float ed  = expf(v2 - v1);
        const float wt1 = 1.f / (1.f + ed);
        const float wt2 = ed / (1.f + ed);
        // full softmax over 64 experts (max is v1)
        const float p = expf(l - v1);
        float Z = p;
        #pragma unroll
        for (int off = 32; off >= 1; off >>= 1) Z += __shfl_xor(Z, off);
        sumP += p / Z;
        if (lane == 0) {
            const size_t o = (size_t)(m0 + m) * 2;
            out_w[o]     = wt1;
            out_w[o + 1] = wt2;
            out_i[o]     = (float)i1;
            out_i[o + 1] = (float)i2;
            atomicAdd(&cntl[i1], 1);
            atomicAdd(&cntl[i2], 1);
        }
    }
    pred[wave][lane] = sumP;
    __syncthreads();
    if (tid < NEXP) {
        const float s = pred[0][tid] + pred[1][tid] + pred[2][tid] + pred[3][tid];
        wsP[(size_t)blockIdx.x * NEXP + tid] = s;
        wsC[(size_t)blockIdx.x * NEXP + tid] = cntl[tid];
    }
}

__global__ void router_finalize(const float* __restrict__ wsP, const int* __restrict__ wsC,
                                float* __restrict__ out_loss)
{
    const int e = threadIdx.x;   // 64 threads, lane = expert
    float P = 0.f, C = 0.f;
    for (int b = 0; b < NBLK; ++b) {
        P += wsP[(size_t)b * NEXP + e];
        C += (float)wsC[(size_t)b * NEXP + e];
    }
    float val = (C / (float)N_TOKENS) * (P / (float)N_TOKENS);
    #pragma unroll
    for (int off = 32; off >= 1; off >>= 1) val += __shfl_xor(val, off);
    if (e == 0) out_loss[0] = (float)NEXP * val;
}

extern "C" void kernel_launch(void* const* d_in, const int* in_sizes, int n_in,
                              void* d_out, int out_size, void* d_ws, size_t ws_size,
                              hipStream_t stream) {
    const float* x  = (const float*)d_in[0];
    const float* gw = (const float*)d_in[1];
    float* out   = (float*)d_out;
    float* out_w = out;                        // [N,2] weights
    float* out_i = out + (size_t)N_TOKENS * 2; // [N,2] indices (as floats)
    float* loss  = out + (size_t)N_TOKENS * 4; // scalar
    float* wsP = (float*)d_ws;                                  // [NBLK][64]
    int*   wsC = (int*)((char*)d_ws + (size_t)NBLK * NEXP * 4); // [NBLK][64]
    hipLaunchKernelGGL(router_main, dim3(NBLK), dim3(256), 0, stream,
                       x, gw, out_w, out_i, wsP, wsC);
    hipLaunchKernelGGL(router_finalize, dim3(1), dim3(64), 0, stream, wsP, wsC, loss);
}